// Round 4
// baseline (81.639 us; speedup 1.0000x reference)
//
#include <hip/hip_runtime.h>
#include <math.h>

#define N_G   4096
#define NB    256        // blocks == CUs; one 16x16-px tile per block
#define NT    256
#define W_IMG 256
#define H_IMG 256

// software grid barrier: cnt/gen in global ws (memset to 0 each launch)
__device__ __forceinline__ void grid_barrier(int* cnt, int* gen, int nblocks)
{
  __syncthreads();
  if (threadIdx.x == 0) {
    int g = __hip_atomic_load(gen, __ATOMIC_RELAXED, __HIP_MEMORY_SCOPE_AGENT);
    __threadfence();  // agent-scope release: publish this block's writes
    int a = __hip_atomic_fetch_add(cnt, 1, __ATOMIC_ACQ_REL,
                                   __HIP_MEMORY_SCOPE_AGENT) + 1;
    if (a == nblocks) {
      __hip_atomic_store(cnt, 0, __ATOMIC_RELAXED, __HIP_MEMORY_SCOPE_AGENT);
      __hip_atomic_store(gen, g + 1, __ATOMIC_RELEASE, __HIP_MEMORY_SCOPE_AGENT);
    } else {
      while (__hip_atomic_load(gen, __ATOMIC_ACQUIRE,
                               __HIP_MEMORY_SCOPE_AGENT) == g)
        __builtin_amdgcn_s_sleep(2);
    }
    __threadfence();  // agent-scope acquire: invalidate stale cache lines
  }
  __syncthreads();
}

__global__ __launch_bounds__(NT) void splat_all(
    const float* __restrict__ pos, const float* __restrict__ scl,
    const float* __restrict__ rot, const float* __restrict__ col,
    const float* __restrict__ opa, const float* __restrict__ vm,
    int* __restrict__ bar,            // [0]=cnt [1]=gen, zeroed per launch
    float4* __restrict__ gaussS,      // 4*N_G sorted-order packed gaussians
    float4* __restrict__ bboxS,       // N_G sorted-order bboxes
    float* __restrict__ out)
{
  __shared__ __align__(16) char smem[32 * 1024 + 32];
  float* sdep  = (float*)smem;                  // P1: 4096 depths (16KB)
  int*   ilist = (int*)smem;                    // P2/P3: tile list (16KB)
  char*  aux   = smem + 16 * 1024;
  int*   pr    = (int*)aux;                     // P1: 256 partial ranks
  unsigned long long* msk = (unsigned long long*)aux;   // P2: 64 masks
  int*   cnts  = (int*)(aux + 512);             // P2
  int*   offs  = (int*)(aux + 768);             // P2
  float4* sgA  = (float4*)aux;                  // P3 stage: 4x 4KB
  float4* sgB  = (float4*)(aux + 4096);
  float4* sgC  = (float4*)(aux + 8192);
  float4* sgD  = (float4*)(aux + 12288);
  int* tlenp   = (int*)(smem + 32 * 1024);
  int* ndflag  = (int*)(smem + 32 * 1024 + 4);

  const int tid = threadIdx.x;
  const int bid = blockIdx.x;
  const float FX = 300.f, FY = 300.f, CXc = 128.f, CYc = 128.f;

  // ---------- P0: prep 16 gaussians per block, results stay in registers ----
  float g_u=0,g_v=0,g_ia=0,g_ibc=0,g_idd=0,g_o=0;
  float g_cR=0,g_cG=0,g_cB=0,g_Lx=1e9f,g_Ux=-1e9f,g_Ly=1e9f,g_Uy=-1e9f;
  if (tid < 16) {
    int i = bid * 16 + tid;
    float V00=vm[0],V01=vm[1],V02=vm[2],V03=vm[3];
    float V10=vm[4],V11=vm[5],V12=vm[6],V13=vm[7];
    float V20=vm[8],V21=vm[9],V22=vm[10],V23=vm[11];
    float p0=pos[3*i], p1=pos[3*i+1], p2=pos[3*i+2];
    float X = V00*p0+V01*p1+V02*p2+V03;
    float Y = V10*p0+V11*p1+V12*p2+V13;
    float Z = V20*p0+V21*p1+V22*p2+V23;
    float depth = -Z;
    float zp = Z + 1e-8f;
    float sgn = (zp>0.f)?1.f:((zp<0.f)?-1.f:0.f);
    float z_safe = fmaxf(fabsf(Z), 0.01f) * sgn;
    float z2 = z_safe*z_safe;
    float qw=rot[4*i], qx=rot[4*i+1], qy=rot[4*i+2], qz=rot[4*i+3];
    float qi = 1.f/sqrtf(qw*qw+qx*qx+qy*qy+qz*qz);
    qw*=qi; qx*=qi; qy*=qi; qz*=qi;
    float R00=1.f-2.f*qy*qy-2.f*qz*qz, R01=2.f*qx*qy-2.f*qw*qz, R02=2.f*qx*qz+2.f*qw*qy;
    float R10=2.f*qx*qy+2.f*qw*qz, R11=1.f-2.f*qx*qx-2.f*qz*qz, R12=2.f*qy*qz-2.f*qw*qx;
    float R20=2.f*qx*qz-2.f*qw*qy, R21=2.f*qy*qz+2.f*qw*qx, R22=1.f-2.f*qx*qx-2.f*qy*qy;
    float C00=V00*R00+V01*R10+V02*R20, C01=V00*R01+V01*R11+V02*R21, C02=V00*R02+V01*R12+V02*R22;
    float C10=V10*R00+V11*R10+V12*R20, C11=V10*R01+V11*R11+V12*R21, C12=V10*R02+V11*R12+V12*R22;
    float C20=V20*R00+V21*R10+V22*R20, C21=V20*R01+V21*R11+V22*R21, C22=V20*R02+V21*R12+V22*R22;
    float s0=scl[3*i], s1=scl[3*i+1], s2=scl[3*i+2];
    float S00=C00*s0,S01=C01*s1,S02=C02*s2;
    float S10=C10*s0,S11=C11*s1,S12=C12*s2;
    float S20=C20*s0,S21=C21*s1,S22=C22*s2;
    float c00=S00*S00+S01*S01+S02*S02;
    float c01=S00*S10+S01*S11+S02*S12;
    float c02=S00*S20+S01*S21+S02*S22;
    float c11=S10*S10+S11*S11+S12*S12;
    float c12=S10*S20+S11*S21+S12*S22;
    float c22=S20*S20+S21*S21+S22*S22;
    float j00=FX/(-z_safe), j02=FX*X/z2;
    float j11=FY/z_safe,    j12=FY*Y/z2;
    float M00=j00*c00+j02*c02, M01=j00*c01+j02*c12, M02=j00*c02+j02*c22;
    float M10=j11*c01+j12*c02, M11=j11*c11+j12*c12, M12=j11*c12+j12*c22;
    float a =M00*j00+M02*j02;
    float b =M01*j11+M02*j12;
    float c_=M10*j00+M12*j02;
    float d =M11*j11+M12*j12;
    float u = FX*X/(-z_safe)+CXc;
    float v = FY*(-Y)/(-z_safe)+CYc;
    float tr=a+d;
    float det=fmaxf(a*d-b*c_, 1e-6f);
    float disc=fmaxf(tr*tr-4.f*det, 0.f);
    float lam=(tr+sqrtf(disc))*0.5f;
    float radius=fminf(3.f*sqrtf(fmaxf(lam,1e-6f)), 64.f);
    bool vis = (depth>0.01f)&&(depth<100.f)
            && (u+radius>0.f)&&(u-radius<(float)W_IMG)
            && (v+radius>0.f)&&(v-radius<(float)H_IMG);
    float o = vis ? opa[i] : 0.f;
    float ar=a+1e-4f, dr=d+1e-4f;
    float inv_det=1.f/(ar*dr-b*c_);
    g_u=u; g_v=v;
    g_ia=dr*inv_det; g_ibc=(-b*inv_det)+(-c_*inv_det); g_idd=ar*inv_det;
    g_o=o; g_cR=col[3*i]; g_cG=col[3*i+1]; g_cB=col[3*i+2];
    if (o>0.f) {
      g_Lx=truncf(u-radius); g_Ux=truncf(u+radius);
      g_Ly=truncf(v-radius); g_Uy=truncf(v+radius);
    }
  }

  // ---------- P1: stable rank of this block's 16 gaussians, scatter --------
  for (int j = tid; j < N_G; j += NT) sdep[j] = -pos[3*j+2];  // depth exact
  __syncthreads();
  {
    int ii = tid & 15, kk = tid >> 4;
    int ig = bid * 16 + ii;
    float di = sdep[ig];
    const float4* s4 = (const float4*)sdep;
    int base = kk * 256;
    int r = 0;
    #pragma unroll 8
    for (int k = 0; k < 64; k++) {
      float4 v = s4[kk*64 + k];
      int j = base + 4*k;
      r += (v.x<di) || ((v.x==di)&&(j  <ig));
      r += (v.y<di) || ((v.y==di)&&(j+1<ig));
      r += (v.z<di) || ((v.z==di)&&(j+2<ig));
      r += (v.w<di) || ((v.w==di)&&(j+3<ig));
    }
    pr[tid] = r;
  }
  __syncthreads();
  if (tid < 16) {
    int rt = 0;
    #pragma unroll
    for (int kk = 0; kk < 16; kk++) rt += pr[tid + 16*kk];
    gaussS[4*rt+0] = make_float4(g_u,  g_v,  g_ia, g_ibc);
    gaussS[4*rt+1] = make_float4(g_idd,g_o,  g_cR, g_cG);
    gaussS[4*rt+2] = make_float4(g_cB, g_Lx, g_Ux, g_Ly);
    gaussS[4*rt+3] = make_float4(g_Uy, 0.f,  0.f,  0.f);
    bboxS[rt]      = make_float4(g_Lx, g_Ux, g_Ly, g_Uy);
  }

  grid_barrier(&bar[0], &bar[1], NB);   // the ONLY grid-wide sync

  // ---------- P2: build this tile's depth-ordered list in LDS --------------
  const int tX = bid & 15, tY = bid >> 4;
  const float X0 = (float)(tX*16), Y0 = (float)(tY*16);
  const float X1 = X0 + 15.f,      Y1 = Y0 + 15.f;
  const int wave = tid >> 6, lane = tid & 63;
  #pragma unroll
  for (int c16 = 0; c16 < 16; c16++) {
    int chunk = wave*16 + c16;
    float4 bb = bboxS[chunk*64 + lane];
    bool pred = (bb.y>=X0)&&(bb.x<=X1)&&(bb.w>=Y0)&&(bb.z<=Y1);
    unsigned long long m = __ballot(pred);
    if (lane == 0) { msk[chunk] = m; cnts[chunk] = __popcll(m); }
  }
  __syncthreads();
  if (wave == 0) {                       // 64-lane scan of chunk counts
    int c = cnts[lane];
    int x = c;
    #pragma unroll
    for (int dlt = 1; dlt < 64; dlt <<= 1) {
      int y = __shfl_up(x, dlt);
      if (lane >= dlt) x += y;
    }
    offs[lane] = x - c;
    if (lane == 63) *tlenp = x;
  }
  __syncthreads();
  #pragma unroll
  for (int c16 = 0; c16 < 16; c16++) {
    int chunk = wave*16 + c16;
    unsigned long long m = msk[chunk];
    int off = offs[chunk];
    if ((m >> lane) & 1ull)
      ilist[off + __popcll(m & ((1ull<<lane)-1ull))] = chunk*64 + lane;
  }
  __syncthreads();

  // ---------- P3: composite this tile, thread == pixel ---------------------
  const float px = X0 + (float)(tid & 15), py = Y0 + (float)(tid >> 4);
  float aR=0.f, aG=0.f, aB=0.f, aA=0.f;
  const int len = *tlenp;
  for (int base = 0; base < len; base += 256) {
    int total = len - base; if (total > 256) total = 256;
    if (tid < total) {
      int sp = ilist[base + tid];
      const float4* g = &gaussS[4*sp];
      sgA[tid]=g[0]; sgB[tid]=g[1]; sgC[tid]=g[2]; sgD[tid]=g[3];
    }
    if (tid == 0) *ndflag = 0;
    __syncthreads();
    for (int k0 = 0; k0 < total; k0 += 32) {
      if (__ballot(aA <= 0.9999f)) {       // wave-level skip when opaque
        int kend = k0 + 32; if (kend > total) kend = total;
        for (int k = k0; k < kend; k++) {
          float4 A=sgA[k], B=sgB[k], C=sgC[k], D=sgD[k];
          float dx = px - A.x, dy = py - A.y;
          float power = -0.5f*(A.z*dx*dx + A.w*dx*dy + B.x*dy*dy);
          bool inside = (px>=C.y)&&(px<=C.z)&&(py>=C.w)&&(py<=D.x);
          float alpha = inside ? B.y*__expf(power) : 0.f;
          float w = alpha*(1.f-aA);
          aR += w*B.z; aG += w*B.w; aB += w*C.x; aA += w;
        }
      }
    }
    if (aA <= 0.9999f) *ndflag = 1;        // benign LDS race (same value)
    __syncthreads();
    if (*ndflag == 0) break;               // all 256 px opaque: exact skip
  }
  const int x = tX*16 + (tid & 15), y = tY*16 + (tid >> 4);
  out[0*H_IMG*W_IMG + y*W_IMG + x] = aR;
  out[1*H_IMG*W_IMG + y*W_IMG + x] = aG;
  out[2*H_IMG*W_IMG + y*W_IMG + x] = aB;
}

extern "C" void kernel_launch(void* const* d_in, const int* in_sizes, int n_in,
                              void* d_out, int out_size, void* d_ws, size_t ws_size,
                              hipStream_t stream)
{
  const float* pos=(const float*)d_in[0];
  const float* scl=(const float*)d_in[1];
  const float* rot=(const float*)d_in[2];
  const float* col=(const float*)d_in[3];
  const float* opa=(const float*)d_in[4];
  const float* vm =(const float*)d_in[5];
  float* out=(float*)d_out;
  char* ws=(char*)d_ws;
  // ws: [0,64) barrier | [256, 256+256K) gaussS | then 64K bboxS  (~321KB)
  int*    bar   =(int*)   (ws);
  float4* gaussS=(float4*)(ws + 256);
  float4* bboxS =(float4*)(ws + 256 + 256*1024);
  hipMemsetAsync(bar, 0, 64, stream);   // barrier cnt/gen = 0 every launch
  splat_all<<<NB, NT, 0, stream>>>(pos,scl,rot,col,opa,vm,bar,gaussS,bboxS,out);
}

// Round 5
// 54.388 us; speedup vs baseline: 1.5011x; 1.5011x over previous
//
#include <hip/hip_runtime.h>
#include <math.h>

#define N_G   4096
#define W_IMG 256
#define H_IMG 256

// ---------- kernel 1: prep 16 gaussians/block + stable rank + scatter ------
__global__ __launch_bounds__(256) void prep_rank(
    const float* __restrict__ pos, const float* __restrict__ scl,
    const float* __restrict__ rot, const float* __restrict__ col,
    const float* __restrict__ opa, const float* __restrict__ vm,
    float4* __restrict__ gaussS, float4* __restrict__ bboxS)
{
  __shared__ float sdep[N_G];     // 16 KB
  __shared__ int   pr[256];

  const int tid = threadIdx.x;
  const int bid = blockIdx.x;
  const float FX = 300.f, FY = 300.f, CXc = 128.f, CYc = 128.f;

  // P0: prep this block's 16 gaussians; results live in registers
  float g_u=0,g_v=0,g_ia=0,g_ibc=0,g_idd=0,g_o=0;
  float g_cR=0,g_cG=0,g_cB=0,g_Lx=1e9f,g_Ux=-1e9f,g_Ly=1e9f,g_Uy=-1e9f;
  if (tid < 16) {
    int i = bid * 16 + tid;
    float V00=vm[0],V01=vm[1],V02=vm[2],V03=vm[3];
    float V10=vm[4],V11=vm[5],V12=vm[6],V13=vm[7];
    float V20=vm[8],V21=vm[9],V22=vm[10],V23=vm[11];
    float p0=pos[3*i], p1=pos[3*i+1], p2=pos[3*i+2];
    float X = V00*p0+V01*p1+V02*p2+V03;
    float Y = V10*p0+V11*p1+V12*p2+V13;
    float Z = V20*p0+V21*p1+V22*p2+V23;
    float depth = -Z;
    float zp = Z + 1e-8f;
    float sgn = (zp>0.f)?1.f:((zp<0.f)?-1.f:0.f);
    float z_safe = fmaxf(fabsf(Z), 0.01f) * sgn;
    float z2 = z_safe*z_safe;
    float qw=rot[4*i], qx=rot[4*i+1], qy=rot[4*i+2], qz=rot[4*i+3];
    float qi = 1.f/sqrtf(qw*qw+qx*qx+qy*qy+qz*qz);
    qw*=qi; qx*=qi; qy*=qi; qz*=qi;
    float R00=1.f-2.f*qy*qy-2.f*qz*qz, R01=2.f*qx*qy-2.f*qw*qz, R02=2.f*qx*qz+2.f*qw*qy;
    float R10=2.f*qx*qy+2.f*qw*qz, R11=1.f-2.f*qx*qx-2.f*qz*qz, R12=2.f*qy*qz-2.f*qw*qx;
    float R20=2.f*qx*qz-2.f*qw*qy, R21=2.f*qy*qz+2.f*qw*qx, R22=1.f-2.f*qx*qx-2.f*qy*qy;
    float C00=V00*R00+V01*R10+V02*R20, C01=V00*R01+V01*R11+V02*R21, C02=V00*R02+V01*R12+V02*R22;
    float C10=V10*R00+V11*R10+V12*R20, C11=V10*R01+V11*R11+V12*R21, C12=V10*R02+V11*R12+V12*R22;
    float C20=V20*R00+V21*R10+V22*R20, C21=V20*R01+V21*R11+V22*R21, C22=V20*R02+V21*R12+V22*R22;
    float s0=scl[3*i], s1=scl[3*i+1], s2=scl[3*i+2];
    float S00=C00*s0,S01=C01*s1,S02=C02*s2;
    float S10=C10*s0,S11=C11*s1,S12=C12*s2;
    float S20=C20*s0,S21=C21*s1,S22=C22*s2;
    float c00=S00*S00+S01*S01+S02*S02;
    float c01=S00*S10+S01*S11+S02*S12;
    float c02=S00*S20+S01*S21+S02*S22;
    float c11=S10*S10+S11*S11+S12*S12;
    float c12=S10*S20+S11*S21+S12*S22;
    float c22=S20*S20+S21*S21+S22*S22;
    float j00=FX/(-z_safe), j02=FX*X/z2;
    float j11=FY/z_safe,    j12=FY*Y/z2;
    float M00=j00*c00+j02*c02, M01=j00*c01+j02*c12, M02=j00*c02+j02*c22;
    float M10=j11*c01+j12*c02, M11=j11*c11+j12*c12, M12=j11*c12+j12*c22;
    float a =M00*j00+M02*j02;
    float b =M01*j11+M02*j12;
    float c_=M10*j00+M12*j02;
    float d =M11*j11+M12*j12;
    float u = FX*X/(-z_safe)+CXc;
    float v = FY*(-Y)/(-z_safe)+CYc;
    float tr=a+d;
    float det=fmaxf(a*d-b*c_, 1e-6f);
    float disc=fmaxf(tr*tr-4.f*det, 0.f);
    float lam=(tr+sqrtf(disc))*0.5f;
    float radius=fminf(3.f*sqrtf(fmaxf(lam,1e-6f)), 64.f);
    bool vis = (depth>0.01f)&&(depth<100.f)
            && (u+radius>0.f)&&(u-radius<(float)W_IMG)
            && (v+radius>0.f)&&(v-radius<(float)H_IMG);
    float o = vis ? opa[i] : 0.f;
    float ar=a+1e-4f, dr=d+1e-4f;
    float inv_det=1.f/(ar*dr-b*c_);
    g_u=u; g_v=v;
    g_ia=dr*inv_det; g_ibc=(-b*inv_det)+(-c_*inv_det); g_idd=ar*inv_det;
    g_o=o; g_cR=col[3*i]; g_cG=col[3*i+1]; g_cB=col[3*i+2];
    if (o>0.f) {
      g_Lx=truncf(u-radius); g_Ux=truncf(u+radius);
      g_Ly=truncf(v-radius); g_Uy=truncf(v+radius);
    }
  }

  // P1: stage exact depths (= -z), stable-rank the block's 16 gaussians
  for (int j = tid; j < N_G; j += 256) sdep[j] = -pos[3*j+2];
  __syncthreads();
  {
    int ii = tid & 15, kk = tid >> 4;          // gaussian x depth-chunk
    int ig = bid * 16 + ii;
    float di = sdep[ig];
    const float4* s4 = (const float4*)sdep;
    int base = kk * 256;
    int r = 0;
    #pragma unroll 8
    for (int k = 0; k < 64; k++) {
      float4 v = s4[kk*64 + k];
      int j = base + 4*k;
      r += (v.x<di) || ((v.x==di)&&(j  <ig));
      r += (v.y<di) || ((v.y==di)&&(j+1<ig));
      r += (v.z<di) || ((v.z==di)&&(j+2<ig));
      r += (v.w<di) || ((v.w==di)&&(j+3<ig));
    }
    pr[tid] = r;
  }
  __syncthreads();
  if (tid < 16) {
    int rt = 0;
    #pragma unroll
    for (int kk = 0; kk < 16; kk++) rt += pr[tid + 16*kk];
    gaussS[4*rt+0] = make_float4(g_u,  g_v,  g_ia, g_ibc);
    gaussS[4*rt+1] = make_float4(g_idd,g_o,  g_cR, g_cG);
    gaussS[4*rt+2] = make_float4(g_cB, g_Lx, g_Ux, g_Ly);
    gaussS[4*rt+3] = make_float4(g_Uy, 0.f,  0.f,  0.f);
    bboxS[rt]      = make_float4(g_Lx, g_Ux, g_Ly, g_Uy);
  }
}

// ---------- kernel 2: per-tile cull (in LDS) + composite, 1 wave/tile ------
__global__ __launch_bounds__(64) void cull_render(
    const float4* __restrict__ bboxS, const float4* __restrict__ gaussS,
    float* __restrict__ out)
{
  __shared__ unsigned long long smsk[64];
  __shared__ int scnt[64], soff[64];
  __shared__ int ilist[N_G];                 // 16 KB: no CAP, exact
  __shared__ float4 sgA[64], sgB[64], sgC[64], sgD[64];

  const int lane = threadIdx.x;              // block == one wave64
  const int tX = blockIdx.x & 31, tY = blockIdx.x >> 5;
  const float X0=(float)(tX*8), Y0=(float)(tY*8);
  const float X1=X0+7.f, Y1=Y0+7.f;

  // build this tile's depth-ordered list
  #pragma unroll 8
  for (int c = 0; c < 64; c++) {
    float4 bb = bboxS[c*64 + lane];
    bool pred = (bb.y>=X0)&&(bb.x<=X1)&&(bb.w>=Y0)&&(bb.z<=Y1);
    unsigned long long m = __ballot(pred);
    if (lane == 0) { smsk[c] = m; scnt[c] = __popcll(m); }
  }
  __syncthreads();
  int cc = scnt[lane];
  int x = cc;
  #pragma unroll
  for (int d = 1; d < 64; d <<= 1) {
    int y = __shfl_up(x, d);
    if (lane >= d) x += y;
  }
  soff[lane] = x - cc;
  const int len = __shfl(x, 63);             // wave-uniform total
  __syncthreads();
  #pragma unroll 8
  for (int c = 0; c < 64; c++) {
    unsigned long long m = smsk[c];
    int off = soff[c];
    if ((m >> lane) & 1ull)
      ilist[off + __popcll(m & ((1ull<<lane)-1ull))] = c*64 + lane;
  }
  __syncthreads();

  // composite (dense, sorted, early-out)
  const float px = X0 + (float)(lane & 7), py = Y0 + (float)(lane >> 3);
  float aR=0.f, aG=0.f, aB=0.f, aA=0.f;
  for (int base = 0; base < len; base += 64) {
    int total = len - base; if (total > 64) total = 64;
    if (lane < total) {
      int sp = ilist[base + lane];
      const float4* g = &gaussS[4*sp];
      sgA[lane]=g[0]; sgB[lane]=g[1]; sgC[lane]=g[2]; sgD[lane]=g[3];
    }
    __syncthreads();
    float4 A=sgA[0],B=sgB[0],C=sgC[0],D=sgD[0];
    for (int k = 0; k < total; k++) {
      int kn = (k+1<total)?(k+1):k;
      float4 An=sgA[kn],Bn=sgB[kn],Cn=sgC[kn],Dn=sgD[kn];   // prefetch
      float dx=px-A.x, dy=py-A.y;
      float power = -0.5f*(A.z*dx*dx + A.w*dx*dy + B.x*dy*dy);
      bool inside = (px>=C.y)&&(px<=C.z)&&(py>=C.w)&&(py<=D.x);
      float alpha = inside ? B.y*__expf(power) : 0.f;
      float w = alpha*(1.f-aA);
      aR += w*B.z; aG += w*B.w; aB += w*C.x; aA += w;
      A=An;B=Bn;C=Cn;D=Dn;
    }
    __syncthreads();
    if (__ballot(aA <= 0.9999f) == 0ull) break;   // residual < 1e-4
  }
  const int xq = tX*8 + (lane & 7), yq = tY*8 + (lane >> 3);
  out[0*H_IMG*W_IMG + yq*W_IMG + xq] = aR;
  out[1*H_IMG*W_IMG + yq*W_IMG + xq] = aG;
  out[2*H_IMG*W_IMG + yq*W_IMG + xq] = aB;
}

extern "C" void kernel_launch(void* const* d_in, const int* in_sizes, int n_in,
                              void* d_out, int out_size, void* d_ws, size_t ws_size,
                              hipStream_t stream)
{
  const float* pos=(const float*)d_in[0];
  const float* scl=(const float*)d_in[1];
  const float* rot=(const float*)d_in[2];
  const float* col=(const float*)d_in[3];
  const float* opa=(const float*)d_in[4];
  const float* vm =(const float*)d_in[5];
  float* out=(float*)d_out;
  char* ws=(char*)d_ws;
  float4* gaussS=(float4*)(ws);               // 256 KB
  float4* bboxS =(float4*)(ws + 256*1024);    // 64 KB
  prep_rank<<<N_G/16, 256, 0, stream>>>(pos,scl,rot,col,opa,vm,gaussS,bboxS);
  cull_render<<<1024, 64, 0, stream>>>(bboxS,gaussS,out);
}

// Round 6
// 29.464 us; speedup vs baseline: 2.7708x; 1.8459x over previous
//
#include <hip/hip_runtime.h>
#include <math.h>

#define N_G   4096
#define W_IMG 256
#define H_IMG 256

// ---------- kernel 1: prep 16 gaussians/block + stable rank + scatter ------
__global__ __launch_bounds__(256) void prep_rank(
    const float* __restrict__ pos, const float* __restrict__ scl,
    const float* __restrict__ rot, const float* __restrict__ col,
    const float* __restrict__ opa, const float* __restrict__ vm,
    float4* __restrict__ gaussS, float4* __restrict__ bboxS)
{
  __shared__ float sdep[N_G];     // 16 KB
  __shared__ int   pr[256];

  const int tid = threadIdx.x;
  const int bid = blockIdx.x;
  const float FX = 300.f, FY = 300.f, CXc = 128.f, CYc = 128.f;

  // P0: prep this block's 16 gaussians; results live in registers
  float g_u=0,g_v=0,g_ia=0,g_ibc=0,g_idd=0,g_o=0;
  float g_cR=0,g_cG=0,g_cB=0,g_Lx=1e9f,g_Ux=-1e9f,g_Ly=1e9f,g_Uy=-1e9f;
  if (tid < 16) {
    int i = bid * 16 + tid;
    float V00=vm[0],V01=vm[1],V02=vm[2],V03=vm[3];
    float V10=vm[4],V11=vm[5],V12=vm[6],V13=vm[7];
    float V20=vm[8],V21=vm[9],V22=vm[10],V23=vm[11];
    float p0=pos[3*i], p1=pos[3*i+1], p2=pos[3*i+2];
    float X = V00*p0+V01*p1+V02*p2+V03;
    float Y = V10*p0+V11*p1+V12*p2+V13;
    float Z = V20*p0+V21*p1+V22*p2+V23;
    float depth = -Z;
    float zp = Z + 1e-8f;
    float sgn = (zp>0.f)?1.f:((zp<0.f)?-1.f:0.f);
    float z_safe = fmaxf(fabsf(Z), 0.01f) * sgn;
    float z2 = z_safe*z_safe;
    float qw=rot[4*i], qx=rot[4*i+1], qy=rot[4*i+2], qz=rot[4*i+3];
    float qi = 1.f/sqrtf(qw*qw+qx*qx+qy*qy+qz*qz);
    qw*=qi; qx*=qi; qy*=qi; qz*=qi;
    float R00=1.f-2.f*qy*qy-2.f*qz*qz, R01=2.f*qx*qy-2.f*qw*qz, R02=2.f*qx*qz+2.f*qw*qy;
    float R10=2.f*qx*qy+2.f*qw*qz, R11=1.f-2.f*qx*qx-2.f*qz*qz, R12=2.f*qy*qz-2.f*qw*qx;
    float R20=2.f*qx*qz-2.f*qw*qy, R21=2.f*qy*qz+2.f*qw*qx, R22=1.f-2.f*qx*qx-2.f*qy*qy;
    float C00=V00*R00+V01*R10+V02*R20, C01=V00*R01+V01*R11+V02*R21, C02=V00*R02+V01*R12+V02*R22;
    float C10=V10*R00+V11*R10+V12*R20, C11=V10*R01+V11*R11+V12*R21, C12=V10*R02+V11*R12+V12*R22;
    float C20=V20*R00+V21*R10+V22*R20, C21=V20*R01+V21*R11+V22*R21, C22=V20*R02+V21*R12+V22*R22;
    float s0=scl[3*i], s1=scl[3*i+1], s2=scl[3*i+2];
    float S00=C00*s0,S01=C01*s1,S02=C02*s2;
    float S10=C10*s0,S11=C11*s1,S12=C12*s2;
    float S20=C20*s0,S21=C21*s1,S22=C22*s2;
    float c00=S00*S00+S01*S01+S02*S02;
    float c01=S00*S10+S01*S11+S02*S12;
    float c02=S00*S20+S01*S21+S02*S22;
    float c11=S10*S10+S11*S11+S12*S12;
    float c12=S10*S20+S11*S21+S12*S22;
    float c22=S20*S20+S21*S21+S22*S22;
    float j00=FX/(-z_safe), j02=FX*X/z2;
    float j11=FY/z_safe,    j12=FY*Y/z2;
    float M00=j00*c00+j02*c02, M01=j00*c01+j02*c12, M02=j00*c02+j02*c22;
    float M10=j11*c01+j12*c02, M11=j11*c11+j12*c12, M12=j11*c12+j12*c22;
    float a =M00*j00+M02*j02;
    float b =M01*j11+M02*j12;
    float c_=M10*j00+M12*j02;
    float d =M11*j11+M12*j12;
    float u = FX*X/(-z_safe)+CXc;
    float v = FY*(-Y)/(-z_safe)+CYc;
    float tr=a+d;
    float det=fmaxf(a*d-b*c_, 1e-6f);
    float disc=fmaxf(tr*tr-4.f*det, 0.f);
    float lam=(tr+sqrtf(disc))*0.5f;
    float radius=fminf(3.f*sqrtf(fmaxf(lam,1e-6f)), 64.f);
    bool vis = (depth>0.01f)&&(depth<100.f)
            && (u+radius>0.f)&&(u-radius<(float)W_IMG)
            && (v+radius>0.f)&&(v-radius<(float)H_IMG);
    float o = vis ? opa[i] : 0.f;
    float ar=a+1e-4f, dr=d+1e-4f;
    float inv_det=1.f/(ar*dr-b*c_);
    g_u=u; g_v=v;
    g_ia=dr*inv_det; g_ibc=(-b*inv_det)+(-c_*inv_det); g_idd=ar*inv_det;
    g_o=o; g_cR=col[3*i]; g_cG=col[3*i+1]; g_cB=col[3*i+2];
    if (o>0.f) {
      g_Lx=truncf(u-radius); g_Ux=truncf(u+radius);
      g_Ly=truncf(v-radius); g_Uy=truncf(v+radius);
    }
  }

  // P1: stage exact depths (= -z) via float4 loads, then stable rank
  {
    const float4* p4 = (const float4*)pos;
    for (int i4 = tid; i4 < N_G/4; i4 += 256) {
      float4 v0 = p4[3*i4], v1 = p4[3*i4+1], v2 = p4[3*i4+2];
      sdep[4*i4+0] = -v0.z;
      sdep[4*i4+1] = -v1.y;
      sdep[4*i4+2] = -v2.x;
      sdep[4*i4+3] = -v2.w;
    }
  }
  __syncthreads();
  {
    int ii = tid & 15, kk = tid >> 4;          // gaussian x depth-chunk
    int ig = bid * 16 + ii;
    float di = sdep[ig];
    const float4* s4 = (const float4*)sdep;
    int base = kk * 256;
    int r = 0;
    #pragma unroll 8
    for (int k = 0; k < 64; k++) {
      float4 v = s4[kk*64 + k];
      int j = base + 4*k;
      r += (v.x<di) || ((v.x==di)&&(j  <ig));
      r += (v.y<di) || ((v.y==di)&&(j+1<ig));
      r += (v.z<di) || ((v.z==di)&&(j+2<ig));
      r += (v.w<di) || ((v.w==di)&&(j+3<ig));
    }
    pr[tid] = r;
  }
  __syncthreads();
  if (tid < 16) {
    int rt = 0;
    #pragma unroll
    for (int kk = 0; kk < 16; kk++) rt += pr[tid + 16*kk];
    gaussS[4*rt+0] = make_float4(g_u,  g_v,  g_ia, g_ibc);
    gaussS[4*rt+1] = make_float4(g_idd,g_o,  g_cR, g_cG);
    gaussS[4*rt+2] = make_float4(g_cB, g_Lx, g_Ux, g_Ly);
    gaussS[4*rt+3] = make_float4(g_Uy, 0.f,  0.f,  0.f);
    bboxS[rt]      = make_float4(g_Lx, g_Ux, g_Ly, g_Uy);
  }
}

// ---------- kernel 2: cull + segmented composite, 4 waves per 8x8 tile -----
// "over" is associative: wave w composites depth-segment w of the tile list;
// segments are combined in order at the end. Per-wave early-out stays exact
// (a wave's own alpha saturation bounds its own segment's residual).
__global__ __launch_bounds__(256) void cull_render(
    const float4* __restrict__ bboxS, const float4* __restrict__ gaussS,
    float* __restrict__ out)
{
  __shared__ unsigned long long smsk[64];
  __shared__ int scnt[64], soff[64], slen;
  __shared__ int ilist[N_G];                 // 16 KB: exact, no CAP
  __shared__ float4 stage[4][256];           // per-wave 64 gaussians (16 KB)
  __shared__ float4 res[4][64];              // per-wave segment RGBA (4 KB)

  const int tid = threadIdx.x;
  const int wv = tid >> 6, lane = tid & 63;
  const int tX = blockIdx.x & 31, tY = blockIdx.x >> 5;
  const float X0=(float)(tX*8), Y0=(float)(tY*8);
  const float X1=X0+7.f, Y1=Y0+7.f;

  // build this tile's depth-ordered list (4 waves cooperate)
  #pragma unroll
  for (int c16 = 0; c16 < 16; c16++) {
    int c = wv*16 + c16;
    float4 bb = bboxS[c*64 + lane];
    bool pred = (bb.y>=X0)&&(bb.x<=X1)&&(bb.w>=Y0)&&(bb.z<=Y1);
    unsigned long long m = __ballot(pred);
    if (lane == 0) { smsk[c] = m; scnt[c] = __popcll(m); }
  }
  __syncthreads();
  if (wv == 0) {                             // 64-lane scan of chunk counts
    int cc = scnt[lane];
    int x = cc;
    #pragma unroll
    for (int d = 1; d < 64; d <<= 1) {
      int y = __shfl_up(x, d);
      if (lane >= d) x += y;
    }
    soff[lane] = x - cc;
    if (lane == 63) slen = x;
  }
  __syncthreads();
  #pragma unroll
  for (int c16 = 0; c16 < 16; c16++) {
    int c = wv*16 + c16;
    unsigned long long m = smsk[c];
    int off = soff[c];
    if ((m >> lane) & 1ull)
      ilist[off + __popcll(m & ((1ull<<lane)-1ull))] = c*64 + lane;
  }
  __syncthreads();

  // segmented composite: wave w owns [s,e) of the sorted list
  const int len = slen;
  const int segLen = (len + 3) >> 2;
  const int s = wv * segLen;
  int e = s + segLen; if (e > len) e = len;

  const float px = X0 + (float)(lane & 7), py = Y0 + (float)(lane >> 3);
  float aR=0.f, aG=0.f, aB=0.f, aA=0.f;
  for (int base = s; base < e; base += 64) {
    int total = e - base; if (total > 64) total = 64;
    if (lane < total) {
      int sp = ilist[base + lane];
      const float4* g = &gaussS[4*sp];
      float4* st = &stage[wv][4*lane];
      st[0]=g[0]; st[1]=g[1]; st[2]=g[2]; st[3]=g[3];
    }
    // wave-local staging: lanes are lockstep; drain LDS writes, fence sched
    asm volatile("s_waitcnt lgkmcnt(0)" ::: "memory");
    __builtin_amdgcn_wave_barrier();
    const float4* stg = stage[wv];
    for (int k0 = 0; k0 < total; k0 += 32) {
      if (__ballot(aA <= 0.9999f)) {         // wave skip when saturated
        int kend = k0 + 32; if (kend > total) kend = total;
        for (int k = k0; k < kend; k++) {
          float4 A=stg[4*k], B=stg[4*k+1], C=stg[4*k+2], D=stg[4*k+3];
          float dx = px - A.x, dy = py - A.y;
          float power = -0.5f*(A.z*dx*dx + A.w*dx*dy + B.x*dy*dy);
          bool inside = (px>=C.y)&&(px<=C.z)&&(py>=C.w)&&(py<=D.x);
          float alpha = inside ? B.y*__expf(power) : 0.f;
          float w = alpha*(1.f-aA);
          aR += w*B.z; aG += w*B.w; aB += w*C.x; aA += w;
          (void)D;
        }
      }
    }
    __builtin_amdgcn_wave_barrier();
    asm volatile("s_waitcnt lgkmcnt(0)" ::: "memory");
  }
  res[wv][lane] = make_float4(aR, aG, aB, aA);
  __syncthreads();

  // combine segments front-to-back and store
  if (wv == 0) {
    float4 P = res[0][lane];
    #pragma unroll
    for (int w = 1; w < 4; w++) {
      float4 Q = res[w][lane];
      float t = 1.f - P.w;
      P.x += t*Q.x; P.y += t*Q.y; P.z += t*Q.z; P.w += t*Q.w;
    }
    const int xq = tX*8 + (lane & 7), yq = tY*8 + (lane >> 3);
    out[0*H_IMG*W_IMG + yq*W_IMG + xq] = P.x;
    out[1*H_IMG*W_IMG + yq*W_IMG + xq] = P.y;
    out[2*H_IMG*W_IMG + yq*W_IMG + xq] = P.z;
  }
}

extern "C" void kernel_launch(void* const* d_in, const int* in_sizes, int n_in,
                              void* d_out, int out_size, void* d_ws, size_t ws_size,
                              hipStream_t stream)
{
  const float* pos=(const float*)d_in[0];
  const float* scl=(const float*)d_in[1];
  const float* rot=(const float*)d_in[2];
  const float* col=(const float*)d_in[3];
  const float* opa=(const float*)d_in[4];
  const float* vm =(const float*)d_in[5];
  float* out=(float*)d_out;
  char* ws=(char*)d_ws;
  float4* gaussS=(float4*)(ws);               // 256 KB
  float4* bboxS =(float4*)(ws + 256*1024);    // 64 KB
  prep_rank<<<N_G/16, 256, 0, stream>>>(pos,scl,rot,col,opa,vm,gaussS,bboxS);
  cull_render<<<1024, 256, 0, stream>>>(bboxS,gaussS,out);
}